// Round 3
// baseline (282.937 us; speedup 1.0000x reference)
//
#include <hip/hip_runtime.h>
#include <math.h>

// HOG (skimage-faithful): orientations=8, cell=16x16, 1x1 blocks, L2-Hys.
// Input: fake [B,3,512,512] f32 (NCHW). Output: [B, 32*32*8] f32.
//
// Round 3: I-cache fix. R2's fully-unrolled 8x8x3 body (~30-50KB straight-line
// code, no loop reuse) blew the 32KB per-CU I-cache -> 23% VALUBusy with both
// pipes idle. Now: rolled row loop (#pragma unroll 1), explicit P/C/N/T
// register window rotation, 4 px/lane (wave = 256 cols), prefetch one full
// iteration ahead. Body ~300 insts, I-cache resident.
//
// Block = 256 = 4 waves = 2 row-strips(8 rows) x 2 col-halves(256 cols),
// covering one 16-row cell-row. Grid = B * 32.

namespace {

constexpr int Hh = 512;
constexpr int Ww = 512;
constexpr int CHN = 3;
constexpr int HW = Hh * Ww;
constexpr float TAN22 = 0.41421356237309503f;  // tan(22.5 deg)

__device__ __forceinline__ void load_row4(const float* __restrict__ xb,
                                          int h, int c0, int lane,
                                          float dst[CHN][4]) {
    const int hl = h < 0 ? 0 : (h > Hh - 1 ? Hh - 1 : h);  // clamped halo rows
#pragma unroll
    for (int ch = 0; ch < CHN; ++ch) {
        const float4 v = *(const float4*)(xb + (size_t)ch * HW +
                                          (size_t)hl * Ww + c0 + (lane << 2));
        dst[ch][0] = v.x; dst[ch][1] = v.y; dst[ch][2] = v.z; dst[ch][3] = v.w;
    }
}

__global__ __launch_bounds__(256) void hog_kernel(const float* __restrict__ x,
                                                  float* __restrict__ out) {
    const int b       = blockIdx.x >> 5;
    const int cellrow = blockIdx.x & 31;
    const int tx      = threadIdx.x;
    const int lane    = tx & 63;
    const int wid     = tx >> 6;
    const int colhalf = wid & 1;
    const int strip   = wid >> 1;              // 0..1: which 8-row strip
    const int r0      = cellrow * 16 + strip * 8;
    const int c0      = colhalf << 8;          // 0 or 256

    const float* xb = x + (size_t)b * (CHN * HW);

    const bool bL = (colhalf == 0) & (lane == 0);    // w == 0
    const bool bR = (colhalf == 1) & (lane == 63);   // w == 511
    // halo columns (clamped; clamped cases are exactly the forced-zero borders)
    const int hLoff = (colhalf == 0) ? 0 : 255;      // w = c0-1
    const int hRoff = (colhalf == 0) ? 256 : 511;    // w = c0+256

    float P[CHN][4], C[CHN][4], N[CHN][4], T[CHN][4];
    load_row4(xb, r0 - 1, c0, lane, P);
    load_row4(xb, r0,     c0, lane, C);
    load_row4(xb, r0 + 1, c0, lane, N);

    float hLc[CHN], hRc[CHN], hLn[CHN], hRn[CHN];
#pragma unroll
    for (int ch = 0; ch < CHN; ++ch) {       // current-row halo scalars
        const float* rp = xb + (size_t)ch * HW + (size_t)r0 * Ww;
        hLc[ch] = rp[hLoff];
        hRc[ch] = rp[hRoff];
    }

    float c[8];                              // cumulative thermometer histogram
#pragma unroll
    for (int o = 0; o < 8; ++o) c[o] = 0.f;

#pragma unroll 1                             // keep the body I-cache resident
    for (int hh = 0; hh < 8; ++hh) {
        const int h = r0 + hh;

        // ---- prefetch: row h+2 pixels, row h+1 halos (1 iter of slack) ----
        if (hh < 7) load_row4(xb, h + 2, c0, lane, T);
        {
            const int hn = (h + 1 > Hh - 1) ? Hh - 1 : h + 1;
#pragma unroll
            for (int ch = 0; ch < CHN; ++ch) {
                const float* rp = xb + (size_t)ch * HW + (size_t)hn * Ww;
                hLn[ch] = rp[hLoff];
                hRn[ch] = rp[hRoff];
            }
        }

        const bool rowEdge = (h == 0) | (h == Hh - 1);

        // left/right neighbors of this lane's 4-px run (shuffle + halo)
        float gL[CHN], gR[CHN];
#pragma unroll
        for (int ch = 0; ch < CHN; ++ch) {
            const float su = __shfl_up(C[ch][3], 1, 64);
            const float sd = __shfl_down(C[ch][0], 1, 64);
            gL[ch] = (lane == 0)  ? hLc[ch] : su;
            gR[ch] = (lane == 63) ? hRc[ch] : sd;
        }

#pragma unroll
        for (int i = 0; i < 4; ++i) {
            float bm2 = -1.f, bgr = 0.f, bgc = 0.f;
#pragma unroll
            for (int ch = 0; ch < CHN; ++ch) {
                const float gl  = (i == 0) ? gL[ch] : C[ch][i - 1];
                const float gr_ = (i == 3) ? gR[ch] : C[ch][i + 1];
                float gcol = gr_ - gl;
                if (i == 0) gcol = bL ? 0.f : gcol;     // image col borders
                if (i == 3) gcol = bR ? 0.f : gcol;
                float gv = N[ch][i] - P[ch][i];
                gv = rowEdge ? 0.f : gv;                // image row borders
                const float m2 = fmaf(gv, gv, gcol * gcol);
                if (m2 > bm2) { bm2 = m2; bgr = gv; bgc = gcol; }  // first-max
            }
            const float m = sqrtf(bm2);

            // flip into upper half-plane; (gr==0, gc<0) -> 180 deg -> bin 0
            const bool flip = (bgr < 0.f) | ((bgr == 0.f) & (bgc < 0.f));
            const float bb = flip ? -bgr : bgr;         // >= 0
            const float A  = flip ? -bgc : bgc;
            const float Aa = fabsf(A);
            const float p1 = Aa * TAN22;
            const float p2 = bb * TAN22;
            const bool q2  = (A <= 0.f);                // ori >= 90
            const bool ge1 = (bb >= p1), ge2 = (bb >= Aa), ge3 = (p2 >= Aa);
            const bool gt1 = (bb > p1),  gt2 = (bb > Aa),  gt3 = (p2 > Aa);
            // c[k] == sum of m where ori >= 22.5k; hist by differencing later
            c[0] += m;
            c[1] += (q2 | ge1) ? m : 0.f;
            c[2] += (q2 | ge2) ? m : 0.f;
            c[3] += (q2 | ge3) ? m : 0.f;
            c[4] += q2 ? m : 0.f;
            c[5] += (q2 & !gt3) ? m : 0.f;
            c[6] += (q2 & !gt2) ? m : 0.f;
            c[7] += (q2 & !gt1) ? m : 0.f;
        }

        // ---- rotate window ----
        if (hh < 7) {
#pragma unroll
            for (int ch = 0; ch < CHN; ++ch) {
#pragma unroll
                for (int i = 0; i < 4; ++i) {
                    P[ch][i] = C[ch][i];
                    C[ch][i] = N[ch][i];
                    N[ch][i] = T[ch][i];
                }
                hLc[ch] = hLn[ch];
                hRc[ch] = hRn[ch];
            }
        }
    }

    // 4 consecutive lanes = one 16-col cell: pairwise shuffle reduce
#pragma unroll
    for (int o = 0; o < 8; ++o) {
        c[o] += __shfl_xor(c[o], 1, 64);
        c[o] += __shfl_xor(c[o], 2, 64);
    }

    __shared__ float lh[2][32][9];           // [strip][cell][bin], col 8 = 0
    if (tx < 64) lh[tx >> 5][tx & 31][8] = 0.f;
    if ((lane & 3) == 0) {
        const int cell = (colhalf << 4) + (lane >> 2);
#pragma unroll
        for (int o = 0; o < 8; ++o) lh[strip][cell][o] = c[o];
    }
    __syncthreads();

    // 256 threads -> (cell 0..31, bin 0..7): finish hist + L2-Hys
    const int cell = tx >> 3;
    const int o    = tx & 7;
    const float c_o  = lh[0][cell][o]     + lh[1][cell][o];
    const float c_o1 = lh[0][cell][o + 1] + lh[1][cell][o + 1];
    const float hv = (c_o - c_o1) * (1.0f / 256.0f);   // cell mean

    float ss = hv * hv;                      // L2-Hys over the 8-bin group
    ss += __shfl_xor(ss, 1, 64);
    ss += __shfl_xor(ss, 2, 64);
    ss += __shfl_xor(ss, 4, 64);
    float n1 = hv / sqrtf(ss + 1e-10f);      // eps^2 = (1e-5)^2
    n1 = fminf(n1, 0.2f);
    float s2 = n1 * n1;
    s2 += __shfl_xor(s2, 1, 64);
    s2 += __shfl_xor(s2, 2, 64);
    s2 += __shfl_xor(s2, 4, 64);
    const float nv = n1 / sqrtf(s2 + 1e-10f);

    out[(((size_t)b * 32 + cellrow) * 32 + cell) * 8 + o] = nv;
}

} // namespace

extern "C" void kernel_launch(void* const* d_in, const int* in_sizes, int n_in,
                              void* d_out, int out_size, void* d_ws, size_t ws_size,
                              hipStream_t stream) {
    (void)n_in; (void)out_size; (void)d_ws; (void)ws_size;
    const float* x = (const float*)d_in[0];
    float* out = (float*)d_out;
    const int B = in_sizes[0] / (CHN * HW);   // 64 for the bench shape
    const int grid = B * 32;                  // batch * cell-rows
    hog_kernel<<<grid, 256, 0, stream>>>(x, out);
}

// Round 4
// 269.129 us; speedup vs baseline: 1.0513x; 1.0513x over previous
//
#include <hip/hip_runtime.h>
#include <math.h>

// HOG (skimage-faithful): orientations=8, cell=16x16, 1x1 blocks, L2-Hys.
// Input: fake [B,3,512,512] f32 (NCHW). Output: [B, 32*32*8] f32.
//
// Round 4: latency fix. R3 still had a per-iteration load->wait->compute
// chain (plus SMEM halo loads sharing lgkmcnt with ds_bpermute shuffles,
// forcing full drains each row). Now: each wave preloads ALL 6 rows x 3 ch
// it needs as 18 back-to-back float4 loads (18 KB in flight, zero in-loop
// VMEM) + all 24 halo scalars in ONE exec-masked load (lanes 0..23,
// broadcast via __shfl at use). Row loop fully unrolled (~8KB body,
// I-cache safe). Grid doubled to 4096 blocks for occupancy.
//
// Block = 256 = 4 waves stacked vertically; wave = 4 rows x 256 cols
// (4 px/lane). Block covers one cell-row x half the image width.
// Grid = B * 32 cellrows * 2 colhalves.

namespace {

constexpr int Hh = 512;
constexpr int Ww = 512;
constexpr int CHN = 3;
constexpr int HW = Hh * Ww;
constexpr float TAN22 = 0.41421356237309503f;  // tan(22.5 deg)

__global__ __launch_bounds__(256, 4) void hog_kernel(const float* __restrict__ x,
                                                     float* __restrict__ out) {
    const int b       = blockIdx.x >> 6;
    const int cellrow = (blockIdx.x >> 1) & 31;
    const int colhalf = blockIdx.x & 1;
    const int tx      = threadIdx.x;
    const int lane    = tx & 63;
    const int wid     = tx >> 6;               // 0..3: 4-row strip in the cell-row
    const int r0      = cellrow * 16 + wid * 4;
    const int c0      = colhalf << 8;          // 0 or 256

    const float* xb = x + (size_t)b * (CHN * HW);

    // ---- preload all 6 rows x 3 ch as 18 independent float4 loads ----
    float4 R[6][CHN];
#pragma unroll
    for (int r = 0; r < 6; ++r) {
        int h = r0 - 1 + r;
        h = h < 0 ? 0 : (h > Hh - 1 ? Hh - 1 : h);   // clamped rows feed
#pragma unroll                                       // forced-zero grow anyway
        for (int ch = 0; ch < CHN; ++ch)
            R[r][ch] = *(const float4*)(xb + (size_t)ch * HW +
                                        (size_t)h * Ww + c0 + (lane << 2));
    }

    // ---- all 24 halo scalars in one exec-masked load (lanes 0..23) ----
    // lane = ch<<3 | row<<1 | side;  side 0 = col c0-1, side 1 = col c0+256
    float halov = 0.f;
    if (lane < 24) {
        const int ch = lane >> 3, r = (lane >> 1) & 3, side = lane & 1;
        int wcol = side ? c0 + 256 : c0 - 1;
        wcol = wcol < 0 ? 0 : (wcol > Ww - 1 ? Ww - 1 : wcol);  // clamped cases
        halov = xb[(size_t)ch * HW + (size_t)(r0 + r) * Ww + wcol];  // are the
    }                                                 // forced-zero col borders

    const bool bL = (colhalf == 0) & (lane == 0);     // w == 0
    const bool bR = (colhalf == 1) & (lane == 63);    // w == 511

    float c[8];                              // cumulative thermometer histogram
#pragma unroll
    for (int o = 0; o < 8; ++o) c[o] = 0.f;

#pragma unroll
    for (int hh = 0; hh < 4; ++hh) {
        const int h = r0 + hh;
        const bool rowEdge = (h == 0) | (h == Hh - 1);

        // left/right neighbors across lanes (+ block-seam halo broadcast)
        float gL[CHN], gR[CHN];
#pragma unroll
        for (int ch = 0; ch < CHN; ++ch) {
            const float su = __shfl_up(R[hh + 1][ch].w, 1, 64);
            const float sd = __shfl_down(R[hh + 1][ch].x, 1, 64);
            const float hl = __shfl(halov, (ch << 3) | (hh << 1), 64);
            const float hr = __shfl(halov, (ch << 3) | (hh << 1) | 1, 64);
            gL[ch] = (lane == 0)  ? hl : su;
            gR[ch] = (lane == 63) ? hr : sd;
        }

#pragma unroll
        for (int i = 0; i < 4; ++i) {
            float bm2 = -1.f, bgr = 0.f, bgc = 0.f;
#pragma unroll
            for (int ch = 0; ch < CHN; ++ch) {
                const float4 pv = R[hh][ch];
                const float4 cv = R[hh + 1][ch];
                const float4 nv = R[hh + 2][ch];
                const float pr_[4] = {pv.x, pv.y, pv.z, pv.w};
                const float cu_[4] = {cv.x, cv.y, cv.z, cv.w};
                const float nx_[4] = {nv.x, nv.y, nv.z, nv.w};
                const float gl  = (i == 0) ? gL[ch] : cu_[i - 1];
                const float gr_ = (i == 3) ? gR[ch] : cu_[i + 1];
                float gcol = gr_ - gl;
                if (i == 0) gcol = bL ? 0.f : gcol;    // image col borders
                if (i == 3) gcol = bR ? 0.f : gcol;
                float gv = nx_[i] - pr_[i];
                gv = rowEdge ? 0.f : gv;               // image row borders
                const float m2 = fmaf(gv, gv, gcol * gcol);
                if (m2 > bm2) { bm2 = m2; bgr = gv; bgc = gcol; }  // first-max
            }
            const float m = sqrtf(bm2);

            // flip into upper half-plane; (gr==0, gc<0) -> 180 deg -> bin 0
            const bool flip = (bgr < 0.f) | ((bgr == 0.f) & (bgc < 0.f));
            const float bb = flip ? -bgr : bgr;        // >= 0
            const float A  = flip ? -bgc : bgc;
            const float Aa = fabsf(A);
            const float p1 = Aa * TAN22;
            const float p2 = bb * TAN22;
            const bool q2  = (A <= 0.f);               // ori >= 90
            const bool ge1 = (bb >= p1), ge2 = (bb >= Aa), ge3 = (p2 >= Aa);
            const bool gt1 = (bb > p1),  gt2 = (bb > Aa),  gt3 = (p2 > Aa);
            // c[k] == sum of m where ori >= 22.5k; hist by differencing later
            c[0] += m;
            c[1] += (q2 | ge1) ? m : 0.f;
            c[2] += (q2 | ge2) ? m : 0.f;
            c[3] += (q2 | ge3) ? m : 0.f;
            c[4] += q2 ? m : 0.f;
            c[5] += (q2 & !gt3) ? m : 0.f;
            c[6] += (q2 & !gt2) ? m : 0.f;
            c[7] += (q2 & !gt1) ? m : 0.f;
        }
    }

    // 4 consecutive lanes = one 16-col cell: pairwise shuffle reduce
#pragma unroll
    for (int o = 0; o < 8; ++o) {
        c[o] += __shfl_xor(c[o], 1, 64);
        c[o] += __shfl_xor(c[o], 2, 64);
    }

    __shared__ float lh[4][16][9];           // [strip][cell][bin], col 8 = 0
    if (tx < 64) lh[tx >> 4][tx & 15][8] = 0.f;
    if ((lane & 3) == 0) {
        const int cell = lane >> 2;
#pragma unroll
        for (int o = 0; o < 8; ++o) lh[wid][cell][o] = c[o];
    }
    __syncthreads();

    // 128 threads -> (cell 0..15, bin 0..7): finish hist + L2-Hys
    if (tx < 128) {
        const int cell = tx >> 3;
        const int o    = tx & 7;
        const float c_o  = lh[0][cell][o]     + lh[1][cell][o] +
                           lh[2][cell][o]     + lh[3][cell][o];
        const float c_o1 = lh[0][cell][o + 1] + lh[1][cell][o + 1] +
                           lh[2][cell][o + 1] + lh[3][cell][o + 1];
        const float hv = (c_o - c_o1) * (1.0f / 256.0f);   // cell mean

        float ss = hv * hv;                  // L2-Hys over the 8-bin group
        ss += __shfl_xor(ss, 1, 64);
        ss += __shfl_xor(ss, 2, 64);
        ss += __shfl_xor(ss, 4, 64);
        float n1 = hv / sqrtf(ss + 1e-10f);  // eps^2 = (1e-5)^2
        n1 = fminf(n1, 0.2f);
        float s2 = n1 * n1;
        s2 += __shfl_xor(s2, 1, 64);
        s2 += __shfl_xor(s2, 2, 64);
        s2 += __shfl_xor(s2, 4, 64);
        const float nv = n1 / sqrtf(s2 + 1e-10f);

        out[(((size_t)b * 32 + cellrow) * 32 + (colhalf * 16 + cell)) * 8 + o] = nv;
    }
}

} // namespace

extern "C" void kernel_launch(void* const* d_in, const int* in_sizes, int n_in,
                              void* d_out, int out_size, void* d_ws, size_t ws_size,
                              hipStream_t stream) {
    (void)n_in; (void)out_size; (void)d_ws; (void)ws_size;
    const float* x = (const float*)d_in[0];
    float* out = (float*)d_out;
    const int B = in_sizes[0] / (CHN * HW);   // 64 for the bench shape
    const int grid = B * 32 * 2;              // batch * cellrows * colhalves
    hog_kernel<<<grid, 256, 0, stream>>>(x, out);
}